// Round 8
// baseline (139.036 us; speedup 1.0000x reference)
//
#include <hip/hip_runtime.h>

#define NB_C 512
#define NB_B 1024

typedef float vf4 __attribute__((ext_vector_type(4)));

// One-pass batchnorm-list. Block-local reduction: each block owns G[l]
// channels x all 1024 rows, so no grid barrier / global atomics are needed.
//   l:      0   1   2   3   4   5     (M = 2l+1)
//   G:     16   4   4   2   2   2     channels per block
//   V:      8   6  10   7   9  11     float4 per (b, channel-group) chunk
//   grid:  32 128 128 256 256 256  -> 1056 blocks
// Per-block bytes = 1024*V*16 = 128..176 KB; phase-2 re-read is L2/L3-hot.
__global__ __launch_bounds__(256)
void bn_onepass(const vf4* __restrict__ f0, const vf4* __restrict__ f1,
                const vf4* __restrict__ f2, const vf4* __restrict__ f3,
                const vf4* __restrict__ f4, const vf4* __restrict__ f5,
                const float* __restrict__ s0, const float* __restrict__ s1,
                const float* __restrict__ s2, const float* __restrict__ s3,
                const float* __restrict__ s4, const float* __restrict__ s5,
                vf4* __restrict__ out)
{
  const int bid = blockIdx.x;
  int l, gidx;
  if      (bid < 32)  { l = 0; gidx = bid;       }
  else if (bid < 160) { l = 1; gidx = bid - 32;  }
  else if (bid < 288) { l = 2; gidx = bid - 160; }
  else if (bid < 544) { l = 3; gidx = bid - 288; }
  else if (bid < 800) { l = 4; gidx = bid - 544; }
  else                { l = 5; gidx = bid - 800; }

  const int M = 2 * l + 1;
  const int G = (l == 0) ? 16 : (l <= 2 ? 4 : 2);   // channels per block
  const int V = (G * M) / 2;                        // vf4 per b-chunk
  const int n_grp = 256 / V;                        // b-rows in flight

  const vf4* fl; const float* sl; int cumM;
  switch (l) {
    case 0: fl = f0; sl = s0; cumM = 0;  break;
    case 1: fl = f1; sl = s1; cumM = 1;  break;
    case 2: fl = f2; sl = s2; cumM = 4;  break;
    case 3: fl = f3; sl = s3; cumM = 9;  break;
    case 4: fl = f4; sl = s4; cumM = 16; break;
    default: fl = f5; sl = s5; cumM = 25; break;
  }

  const int t   = threadIdx.x;
  const int grp = t / V;              // which b-row within an iteration
  const int j   = t % V;              // vf4 index within the chunk
  const bool active = (grp < n_grp);

  // channel (within group) of each float2-pair of this thread's vf4
  const int ca = (2 * j) / M;
  const int cb = (2 * j + 1) / M;

  const int rs4 = 256 * M;            // row stride in float4
  const int c0  = gidx * G;           // first channel of this block
  const vf4* p  = fl + (size_t)gidx * V;          // chunk4 = gidx*G*M/2 = gidx*V
  vf4* q = out + (size_t)262144 * cumM + (size_t)gidx * V;

  __shared__ float lsum[16];
  __shared__ float lsq[16];
  __shared__ float lscale[16];
  if (t < G) { lsum[t] = 0.f; lsq[t] = 0.f; }
  __syncthreads();

  // ---- phase 1: per-thread moments over this thread's b-rows ----
  float sa = 0.f, qa = 0.f, sb = 0.f, qb = 0.f;
  if (active) {
#pragma unroll 4
    for (int b = grp; b < NB_B; b += n_grp) {
      vf4 v = p[(size_t)b * rs4 + j];
      float r0 = v.x * v.x + v.y * v.y;
      float r1 = v.z * v.z + v.w * v.w;
      sa += sqrtf(r0); qa += r0;
      sb += sqrtf(r1); qb += r1;
    }
    atomicAdd(&lsum[ca], sa); atomicAdd(&lsq[ca], qa);
    atomicAdd(&lsum[cb], sb); atomicAdd(&lsq[cb], qb);
  }
  __syncthreads();

  // ---- per-channel scale ----
  if (t < G) {
    const float rc = 1.0f / (float)(NB_B * M);
    const float mean = lsum[t] * rc;
    const float var  = fmaxf(lsq[t] * rc - mean * mean, 0.f);
    const float bstd = sqrtf(var);
    const float nstd = 0.5f * (sl[c0 + t] + bstd);  // CNT=1 blend
    lscale[t] = 1.0f / fmaxf(1e-5f, nstd);
  }
  __syncthreads();

  // ---- phase 2: normalize (re-read is L2/L3-hot; nt store) ----
  if (active) {
    const float sca = lscale[ca];
    const float scb = lscale[cb];
#pragma unroll 4
    for (int b = grp; b < NB_B; b += n_grp) {
      vf4 v = p[(size_t)b * rs4 + j];
      v.x *= sca; v.y *= sca; v.z *= scb; v.w *= scb;
      __builtin_nontemporal_store(v, &q[(size_t)b * rs4 + j]);
    }
  }
}

extern "C" void kernel_launch(void* const* d_in, const int* in_sizes, int n_in,
                              void* d_out, int out_size, void* d_ws, size_t ws_size,
                              hipStream_t stream) {
  bn_onepass<<<1056, 256, 0, stream>>>(
      (const vf4*)d_in[0], (const vf4*)d_in[1], (const vf4*)d_in[2],
      (const vf4*)d_in[3], (const vf4*)d_in[4], (const vf4*)d_in[5],
      (const float*)d_in[6], (const float*)d_in[7], (const float*)d_in[8],
      (const float*)d_in[9], (const float*)d_in[10], (const float*)d_in[11],
      (vf4*)d_out);
}

// Round 9
// 85.334 us; speedup vs baseline: 1.6293x; 1.6293x over previous
//
#include <hip/hip_runtime.h>

#define NB_C 512
#define NB_B 1024
#define SB_RED 64   // B-splits for reduce kernel (16 rows per block, 2304 blocks)
#define SB_NRM 64   // B-splits for normalize kernel

typedef float vf4 __attribute__((ext_vector_type(4)));

// Decode window-linear index wl in [0,36) -> (l, w); returns l, sets w.
// cumM = {0,1,4,9,16,25,36} (cumsum of M=2l+1). Note cumM[l] = wl - w.
__device__ __forceinline__ int decode_lw(int wl, int& w) {
  if (wl < 1)  { w = wl;      return 0; }
  if (wl < 4)  { w = wl - 1;  return 1; }
  if (wl < 9)  { w = wl - 4;  return 2; }
  if (wl < 16) { w = wl - 9;  return 3; }
  if (wl < 25) { w = wl - 16; return 4; }
  w = wl - 25; return 5;
}

__device__ __forceinline__ const vf4* pick_f(int l,
    const vf4* f0, const vf4* f1, const vf4* f2,
    const vf4* f3, const vf4* f4, const vf4* f5) {
  switch (l) {
    case 0: return f0; case 1: return f1; case 2: return f2;
    case 3: return f3; case 4: return f4; default: return f5;
  }
}

__device__ __forceinline__ const float* pick_s(int l,
    const float* s0, const float* s1, const float* s2,
    const float* s3, const float* s4, const float* s5) {
  switch (l) {
    case 0: return s0; case 1: return s1; case 2: return s2;
    case 3: return s3; case 4: return s4; default: return s5;
  }
}

// Pass 1: per-channel sum(norm), sum(norm^2) via private accumulation over
// the B dimension (each thread's channel assignment is loop-invariant),
// then LDS segmented reduce + one global atomicAdd per (block, channel).
// Regular (caching) loads: they populate L2/MALL for pass 2.
__global__ __launch_bounds__(256)
void bn_reduce(const vf4* __restrict__ f0, const vf4* __restrict__ f1,
               const vf4* __restrict__ f2, const vf4* __restrict__ f3,
               const vf4* __restrict__ f4, const vf4* __restrict__ f5,
               float* __restrict__ gsum, float* __restrict__ gsq)
{
  const int bs = blockIdx.x % SB_RED;
  const int wl = blockIdx.x / SB_RED;
  int w; const int l = decode_lw(wl, w);
  const int M = 2 * l + 1;
  const vf4* __restrict__ f = pick_f(l, f0, f1, f2, f3, f4, f5);

  const int t  = threadIdx.x;
  const int o4 = w * 256 + t;          // float4 offset within a row
  const int e0 = 2 * o4;               // float2 (=one [x,y] pair) index
  const int c0 = e0 / M;               // channel of pair 0 (loop-invariant)
  const int c1 = (e0 + 1) / M;         // channel of pair 1
  const int rs4 = 256 * M;             // row stride in float4
  const int Bc  = NB_B / SB_RED;       // 16 rows per block

  const vf4* p = f + (size_t)(bs * Bc) * rs4 + o4;
  float s0 = 0.f, q0 = 0.f, s1 = 0.f, q1 = 0.f;
#pragma unroll
  for (int i = 0; i < Bc; ++i) {
    vf4 v = p[(size_t)i * rs4];
    float r0 = v.x * v.x + v.y * v.y;
    float r1 = v.z * v.z + v.w * v.w;
    s0 += sqrtf(r0); q0 += r0;
    s1 += sqrtf(r1); q1 += r1;
  }

  __shared__ float ls[512];
  __shared__ float lq[512];
  __shared__ short lc[512];
  ls[2*t]   = s0; lq[2*t]   = q0; lc[2*t]   = (short)c0;
  ls[2*t+1] = s1; lq[2*t+1] = q1; lc[2*t+1] = (short)c1;
  __syncthreads();

  const int base = l * NB_C;
#pragma unroll
  for (int k = 0; k < 2; ++k) {
    const int e = 2 * t + k;
    const short c = lc[e];
    if (e == 0 || lc[e-1] != c) {       // segment leader
      float a = 0.f, a2 = 0.f;
      int j = e;
      while (j < 512 && lc[j] == c) { a += ls[j]; a2 += lq[j]; ++j; }
      atomicAdd(&gsum[base + (int)c], a);
      atomicAdd(&gsq [base + (int)c], a2);
    }
  }
}

// Compute reciprocal scale for one channel from the accumulated moments.
__device__ __forceinline__ float chan_scale(float sum, float sq, float rstd,
                                            float cnt) {
  const float mean = sum / cnt;
  const float var  = fmaxf(sq / cnt - mean * mean, 0.f);
  const float bstd = sqrtf(var);
  const float nstd = 0.5f * (rstd + bstd);   // CNT=1: std/2 + bstd/2
  return 1.0f / fmaxf(1e-5f, nstd);
}

// Pass 2: out = f * sinv[channel]. Finalize inlined. Cached loads,
// nt stores (best-known combo from R3/R7 A/B).
__global__ __launch_bounds__(256)
void bn_norm(const vf4* __restrict__ f0, const vf4* __restrict__ f1,
             const vf4* __restrict__ f2, const vf4* __restrict__ f3,
             const vf4* __restrict__ f4, const vf4* __restrict__ f5,
             const float* __restrict__ s0, const float* __restrict__ s1,
             const float* __restrict__ s2, const float* __restrict__ s3,
             const float* __restrict__ s4, const float* __restrict__ s5,
             const float* __restrict__ gsum, const float* __restrict__ gsq,
             vf4* __restrict__ out)
{
  const int bs = blockIdx.x % SB_NRM;
  const int wl = blockIdx.x / SB_NRM;
  int w; const int l = decode_lw(wl, w);
  const int cumM = wl - w;             // cumsum of M below l
  const int M = 2 * l + 1;
  const vf4* __restrict__ f = pick_f(l, f0, f1, f2, f3, f4, f5);
  const float* __restrict__ sp = pick_s(l, s0, s1, s2, s3, s4, s5);

  const int t  = threadIdx.x;
  const int o4 = w * 256 + t;
  const int e0 = 2 * o4;
  const int c0 = e0 / M;
  const int c1 = (e0 + 1) / M;
  const int base = l * NB_C;
  const float cnt = (float)(NB_B * M);
  const float sc0 = chan_scale(gsum[base + c0], gsq[base + c0], sp[c0], cnt);
  const float sc1 = chan_scale(gsum[base + c1], gsq[base + c1], sp[c1], cnt);
  const int rs4 = 256 * M;
  const int Bc  = NB_B / SB_NRM;       // 16 rows per block

  // per-l output base in float4: 1024*512*M*2/4 = 262144*M, cumulative.
  const size_t ob = (size_t)262144 * cumM;
  const size_t tb = (size_t)(bs * Bc) * rs4 + o4;
  const vf4* p = f + tb;
  vf4* q = out + ob + tb;
#pragma unroll
  for (int i = 0; i < Bc; ++i) {
    vf4 v = p[(size_t)i * rs4];
    v.x *= sc0; v.y *= sc0; v.z *= sc1; v.w *= sc1;
    __builtin_nontemporal_store(v, &q[(size_t)i * rs4]);
  }
}

extern "C" void kernel_launch(void* const* d_in, const int* in_sizes, int n_in,
                              void* d_out, int out_size, void* d_ws, size_t ws_size,
                              hipStream_t stream) {
  const vf4* f[6];
  const float* s[6];
  for (int l = 0; l < 6; ++l) {
    f[l] = (const vf4*)d_in[l];
    s[l] = (const float*)d_in[6 + l];
  }
  float* gsum = (float*)d_ws;          // 3072 floats
  float* gsq  = gsum + 6 * NB_C;       // 3072 floats

  (void)hipMemsetAsync(gsum, 0, 2 * 6 * NB_C * sizeof(float), stream);

  bn_reduce<<<36 * SB_RED, 256, 0, stream>>>(
      f[0], f[1], f[2], f[3], f[4], f[5], gsum, gsq);
  bn_norm<<<36 * SB_NRM, 256, 0, stream>>>(
      f[0], f[1], f[2], f[3], f[4], f[5],
      s[0], s[1], s[2], s[3], s[4], s[5],
      gsum, gsq, (vf4*)d_out);
}

// Round 10
// 82.192 us; speedup vs baseline: 1.6916x; 1.0382x over previous
//
#include <hip/hip_runtime.h>

#define NB_C 512
#define NB_B 1024
#define SB_RED 32   // B-splits for reduce kernel (32 rows per block)
#define SB_NRM 32   // B-splits for normalize kernel

typedef float vf4 __attribute__((ext_vector_type(4)));

// Streaming store: bypass L2/MALL allocation (sc0 sc1 nt = gfx940+ "glc slc").
// Goal: keep the 151 MB input resident in the 256 MB Infinity Cache so the
// normalize pass re-reads it from L3 instead of HBM.
__device__ __forceinline__ void store_stream(vf4* addr, vf4 v) {
  asm volatile("global_store_dwordx4 %0, %1, off sc0 sc1 nt"
               :: "v"(addr), "v"(v) : "memory");
}

// Decode window-linear index wl in [0,36) -> (l, w); returns l, sets w.
// cumM = {0,1,4,9,16,25,36} (cumsum of M=2l+1). Note cumM[l] = wl - w.
__device__ __forceinline__ int decode_lw(int wl, int& w) {
  if (wl < 1)  { w = wl;      return 0; }
  if (wl < 4)  { w = wl - 1;  return 1; }
  if (wl < 9)  { w = wl - 4;  return 2; }
  if (wl < 16) { w = wl - 9;  return 3; }
  if (wl < 25) { w = wl - 16; return 4; }
  w = wl - 25; return 5;
}

__device__ __forceinline__ const vf4* pick_f(int l,
    const vf4* f0, const vf4* f1, const vf4* f2,
    const vf4* f3, const vf4* f4, const vf4* f5) {
  switch (l) {
    case 0: return f0; case 1: return f1; case 2: return f2;
    case 3: return f3; case 4: return f4; default: return f5;
  }
}

__device__ __forceinline__ const float* pick_s(int l,
    const float* s0, const float* s1, const float* s2,
    const float* s3, const float* s4, const float* s5) {
  switch (l) {
    case 0: return s0; case 1: return s1; case 2: return s2;
    case 3: return s3; case 4: return s4; default: return s5;
  }
}

// Pass 1: per-channel sum(norm), sum(norm^2) via private accumulation over
// the B dimension (each thread's channel assignment is loop-invariant),
// then LDS segmented reduce + one global atomicAdd per (block, channel).
// Regular (caching) loads: they populate L2/MALL for pass 2.
__global__ __launch_bounds__(256)
void bn_reduce(const vf4* __restrict__ f0, const vf4* __restrict__ f1,
               const vf4* __restrict__ f2, const vf4* __restrict__ f3,
               const vf4* __restrict__ f4, const vf4* __restrict__ f5,
               float* __restrict__ gsum, float* __restrict__ gsq)
{
  const int bs = blockIdx.x % SB_RED;
  const int wl = blockIdx.x / SB_RED;
  int w; const int l = decode_lw(wl, w);
  const int M = 2 * l + 1;
  const vf4* __restrict__ f = pick_f(l, f0, f1, f2, f3, f4, f5);

  const int t  = threadIdx.x;
  const int o4 = w * 256 + t;          // float4 offset within a row
  const int e0 = 2 * o4;               // float2 (=one [x,y] pair) index
  const int c0 = e0 / M;               // channel of pair 0 (loop-invariant)
  const int c1 = (e0 + 1) / M;         // channel of pair 1
  const int rs4 = 256 * M;             // row stride in float4
  const int Bc  = NB_B / SB_RED;       // 32 rows per block

  const vf4* p = f + (size_t)(bs * Bc) * rs4 + o4;
  float s0 = 0.f, q0 = 0.f, s1 = 0.f, q1 = 0.f;
#pragma unroll 8
  for (int i = 0; i < Bc; ++i) {
    vf4 v = p[(size_t)i * rs4];
    float r0 = v.x * v.x + v.y * v.y;
    float r1 = v.z * v.z + v.w * v.w;
    s0 += sqrtf(r0); q0 += r0;
    s1 += sqrtf(r1); q1 += r1;
  }

  __shared__ float ls[512];
  __shared__ float lq[512];
  __shared__ short lc[512];
  ls[2*t]   = s0; lq[2*t]   = q0; lc[2*t]   = (short)c0;
  ls[2*t+1] = s1; lq[2*t+1] = q1; lc[2*t+1] = (short)c1;
  __syncthreads();

  const int base = l * NB_C;
#pragma unroll
  for (int k = 0; k < 2; ++k) {
    const int e = 2 * t + k;
    const short c = lc[e];
    if (e == 0 || lc[e-1] != c) {       // segment leader
      float a = 0.f, a2 = 0.f;
      int j = e;
      while (j < 512 && lc[j] == c) { a += ls[j]; a2 += lq[j]; ++j; }
      atomicAdd(&gsum[base + (int)c], a);
      atomicAdd(&gsq [base + (int)c], a2);
    }
  }
}

// Compute reciprocal scale for one channel from the accumulated moments.
__device__ __forceinline__ float chan_scale(float sum, float sq, float rstd,
                                            float cnt) {
  const float mean = sum / cnt;
  const float var  = fmaxf(sq / cnt - mean * mean, 0.f);
  const float bstd = sqrtf(var);
  const float nstd = 0.5f * (rstd + bstd);   // CNT=1: std/2 + bstd/2
  return 1.0f / fmaxf(1e-5f, nstd);
}

// Pass 2: out = f * sinv[channel]. Finalize inlined. Cached loads
// (input should be L3-resident from pass 1); streaming sc0+sc1+nt stores
// so the write stream does not allocate/evict in L2/MALL.
__global__ __launch_bounds__(256)
void bn_norm(const vf4* __restrict__ f0, const vf4* __restrict__ f1,
             const vf4* __restrict__ f2, const vf4* __restrict__ f3,
             const vf4* __restrict__ f4, const vf4* __restrict__ f5,
             const float* __restrict__ s0, const float* __restrict__ s1,
             const float* __restrict__ s2, const float* __restrict__ s3,
             const float* __restrict__ s4, const float* __restrict__ s5,
             const float* __restrict__ gsum, const float* __restrict__ gsq,
             vf4* __restrict__ out)
{
  const int bs = blockIdx.x % SB_NRM;
  const int wl = blockIdx.x / SB_NRM;
  int w; const int l = decode_lw(wl, w);
  const int cumM = wl - w;             // cumsum of M below l
  const int M = 2 * l + 1;
  const vf4* __restrict__ f = pick_f(l, f0, f1, f2, f3, f4, f5);
  const float* __restrict__ sp = pick_s(l, s0, s1, s2, s3, s4, s5);

  const int t  = threadIdx.x;
  const int o4 = w * 256 + t;
  const int e0 = 2 * o4;
  const int c0 = e0 / M;
  const int c1 = (e0 + 1) / M;
  const int base = l * NB_C;
  const float cnt = (float)(NB_B * M);
  const float sc0 = chan_scale(gsum[base + c0], gsq[base + c0], sp[c0], cnt);
  const float sc1 = chan_scale(gsum[base + c1], gsq[base + c1], sp[c1], cnt);
  const int rs4 = 256 * M;
  const int Bc  = NB_B / SB_NRM;       // 32 rows per block

  // per-l output base in float4: 1024*512*M*2/4 = 262144*M, cumulative.
  const size_t ob = (size_t)262144 * cumM;
  const size_t tb = (size_t)(bs * Bc) * rs4 + o4;
  const vf4* p = f + tb;
  vf4* q = out + ob + tb;
#pragma unroll 8
  for (int i = 0; i < Bc; ++i) {
    vf4 v = p[(size_t)i * rs4];
    v.x *= sc0; v.y *= sc0; v.z *= sc1; v.w *= sc1;
    store_stream(&q[(size_t)i * rs4], v);
  }
}

extern "C" void kernel_launch(void* const* d_in, const int* in_sizes, int n_in,
                              void* d_out, int out_size, void* d_ws, size_t ws_size,
                              hipStream_t stream) {
  const vf4* f[6];
  const float* s[6];
  for (int l = 0; l < 6; ++l) {
    f[l] = (const vf4*)d_in[l];
    s[l] = (const float*)d_in[6 + l];
  }
  float* gsum = (float*)d_ws;          // 3072 floats
  float* gsq  = gsum + 6 * NB_C;       // 3072 floats

  (void)hipMemsetAsync(gsum, 0, 2 * 6 * NB_C * sizeof(float), stream);

  bn_reduce<<<36 * SB_RED, 256, 0, stream>>>(
      f[0], f[1], f[2], f[3], f[4], f[5], gsum, gsq);
  bn_norm<<<36 * SB_NRM, 256, 0, stream>>>(
      f[0], f[1], f[2], f[3], f[4], f[5],
      s[0], s[1], s[2], s[3], s[4], s[5],
      gsum, gsq, (vf4*)d_out);
}